// Round 6
// baseline (133.281 us; speedup 1.0000x reference)
//
#include <hip/hip_runtime.h>

// MaskedDenseMatMul: out[b,h,q,k] = (sum_d a[b,h,q,d]*b[b,h,k,d]) * mask[b,0,q,k]
// B=2 H=8 S=2048 D=64, fp32 in/out.  Memory-bound on the 256 MiB output write.
//
// R6 design — never issue a load after a store (vmcnt is IN-ORDER; a wait on
// any load issued after stores forces those stores to fully drain, serializing
// the write stream; the harness fill kernel hits 7 TB/s precisely because it
// has zero loads):
//  - one fused pre-pass: A,B fp32->bf16 + mask fp32->u8 into d_ws
//  - main kernel: per wave, ALL loads (A frags, 16 mask words, 32 B frags)
//    and MFMAs happen first; the 16 f32x4 stores are the wave's FINAL vmem
//    ops, left un-drained -> deep store pipelining like the fill kernel
//  - no LDS bounce (R3 vs R4 proved 64B-vs-512B store chunks are neutral)
//  - __launch_bounds__(256,3): ~170 VGPR cap -> 12 waves/CU

typedef __attribute__((ext_vector_type(8))) short bf16x8;
typedef __attribute__((ext_vector_type(4))) float f32x4;
typedef __attribute__((ext_vector_type(2))) unsigned int u32x2;

static constexpr int S = 2048;
static constexpr int D = 64;
static constexpr size_t NELEM = (size_t)16 * S * D;   // elems per A/B input
static constexpr size_t NMASK = (size_t)2 * S * S;    // mask elems (B*S*S)

__device__ inline short f2bf(float f) {
    union { float f; unsigned u; } v; v.f = f;
    unsigned r = (v.u + 0x7FFFu + ((v.u >> 16) & 1u)) >> 16;
    return (short)r;
}

// ------------- fused pre-pass: cvt A (1024 blk), cvt B (1024), pack mask (4096)
__global__ __launch_bounds__(256) void prep_kernel(const float* __restrict__ a,
                                                   const float* __restrict__ b,
                                                   const float* __restrict__ m,
                                                   short* __restrict__ a16,
                                                   short* __restrict__ b16,
                                                   unsigned char* __restrict__ m8) {
    const int blk = blockIdx.x;
    if (blk < 2048) {
        const float* src = (blk < 1024) ? a : b;
        short* dst       = (blk < 1024) ? a16 : b16;
        size_t i = ((size_t)(blk & 1023) * 256 + threadIdx.x) * 8;
        f32x4 f0 = *(const f32x4*)(src + i);
        f32x4 f1 = *(const f32x4*)(src + i + 4);
        bf16x8 t;
        t[0] = f2bf(f0[0]); t[1] = f2bf(f0[1]); t[2] = f2bf(f0[2]); t[3] = f2bf(f0[3]);
        t[4] = f2bf(f1[0]); t[5] = f2bf(f1[1]); t[6] = f2bf(f1[2]); t[7] = f2bf(f1[3]);
        *(bf16x8*)(dst + i) = t;
    } else {
        size_t i = ((size_t)(blk - 2048) * 256 + threadIdx.x) * 8;
        f32x4 f0 = *(const f32x4*)(m + i);
        f32x4 f1 = *(const f32x4*)(m + i + 4);
        unsigned w0 = 0, w1 = 0;
        w0 |= (f0[0] != 0.f ? 1u : 0u);
        w0 |= (f0[1] != 0.f ? 1u : 0u) << 8;
        w0 |= (f0[2] != 0.f ? 1u : 0u) << 16;
        w0 |= (f0[3] != 0.f ? 1u : 0u) << 24;
        w1 |= (f1[0] != 0.f ? 1u : 0u);
        w1 |= (f1[1] != 0.f ? 1u : 0u) << 8;
        w1 |= (f1[2] != 0.f ? 1u : 0u) << 16;
        w1 |= (f1[3] != 0.f ? 1u : 0u) << 24;
        u32x2 w; w[0] = w0; w[1] = w1;
        *(u32x2*)(m8 + i) = w;
    }
}

// ------------- main kernel: all loads -> all MFMA -> select -> all stores ----
__global__ __launch_bounds__(256, 3) void masked_mm_bf16_kernel(
    const short* __restrict__ A16,
    const short* __restrict__ B16,
    const unsigned char* __restrict__ M8,
    float* __restrict__ O) {

    const int bh   = blockIdx.z;             // 0..15
    const int bb   = bh >> 3;                // batch
    const int lane = threadIdx.x & 63;
    const int w    = threadIdx.x >> 6;       // wave 0..3

    const int r0 = blockIdx.y * 64 + w * 16; // wave's 16 output rows
    const int c0 = blockIdx.x * 256;         // block's 256 output cols

    const int rlane = lane & 15;             // MFMA operand row within 16
    const int kg    = lane >> 4;             // k-group 0..3

    const short* __restrict__ Ab = A16 + (size_t)bh * S * D;
    const short* __restrict__ Bb = B16 + (size_t)bh * S * D;
    const unsigned char* __restrict__ Mb = M8 + (size_t)bb * S * S;
    float* __restrict__ Ob       = O + (size_t)bh * S * S;

    // A fragments for the wave's 16 rows, K=64 (2 x K=32)
    bf16x8 af0 = *(const bf16x8*)(Ab + (size_t)(r0 + rlane) * D + 0  + kg * 8);
    bf16x8 af1 = *(const bf16x8*)(Ab + (size_t)(r0 + rlane) * D + 32 + kg * 8);

    // mask words in the acc pattern: mw[t] covers O[r0+rlane][c0+t*16+kg*4 ..+3]
    const size_t rowbase = (size_t)(r0 + rlane) * S + c0;
    unsigned mw[16];
#pragma unroll
    for (int t = 0; t < 16; ++t)
        mw[t] = *(const unsigned*)(Mb + rowbase + t * 16 + kg * 4);

    // B fragments + MFMA; swapped operands: acc[t][j] = O[r0+rlane][c0+t*16+kg*4+j]
    f32x4 acc[16];
#pragma unroll
    for (int t = 0; t < 16; ++t) {
        const short* pb = Bb + (size_t)(c0 + t * 16 + rlane) * D + kg * 8;
        bf16x8 b0 = *(const bf16x8*)(pb);
        bf16x8 b1 = *(const bf16x8*)(pb + 32);
        f32x4 z = {0.f, 0.f, 0.f, 0.f};
        z = __builtin_amdgcn_mfma_f32_16x16x32_bf16(b0, af0, z, 0, 0, 0);
        z = __builtin_amdgcn_mfma_f32_16x16x32_bf16(b1, af1, z, 0, 0, 0);
        acc[t] = z;
    }

    // mask select in-register, then the wave's FINAL vmem burst: 16 stores,
    // never drained by any subsequent load
#pragma unroll
    for (int t = 0; t < 16; ++t) {
        f32x4 v = acc[t];
        const unsigned m = mw[t];
        v[0] = (m & 0x000000FFu) ? v[0] : 0.f;
        v[1] = (m & 0x0000FF00u) ? v[1] : 0.f;
        v[2] = (m & 0x00FF0000u) ? v[2] : 0.f;
        v[3] = (m & 0xFF000000u) ? v[3] : 0.f;
        *(f32x4*)(Ob + rowbase + t * 16 + kg * 4) = v;
    }
}

// ---------------- fallback (ws too small): inline conversion -----------------
__global__ __launch_bounds__(256) void masked_mm_f32_kernel(
    const float* __restrict__ A,
    const float* __restrict__ B,
    const float* __restrict__ M,
    float* __restrict__ O) {

    const int bh   = blockIdx.z;
    const int bb   = bh >> 3;
    const int lane = threadIdx.x & 63;
    const int w    = threadIdx.x >> 6;
    const int r0 = blockIdx.y * 64 + w * 16;
    const int c0 = blockIdx.x * 256;
    const int rlane = lane & 15;
    const int kg    = lane >> 4;

    const float* __restrict__ Ab = A + (size_t)bh * S * D;
    const float* __restrict__ Bb = B + (size_t)bh * S * D;
    const float* __restrict__ Mb = M + (size_t)bb * S * S;
    float* __restrict__ Ob       = O + (size_t)bh * S * S;

    const float* pa = Ab + (size_t)(r0 + rlane) * D + kg * 8;
    f32x4 fa0 = *(const f32x4*)pa, fa1 = *(const f32x4*)(pa + 4);
    f32x4 fa2 = *(const f32x4*)(pa + 32), fa3 = *(const f32x4*)(pa + 36);
    bf16x8 af0, af1;
    af0[0]=f2bf(fa0[0]); af0[1]=f2bf(fa0[1]); af0[2]=f2bf(fa0[2]); af0[3]=f2bf(fa0[3]);
    af0[4]=f2bf(fa1[0]); af0[5]=f2bf(fa1[1]); af0[6]=f2bf(fa1[2]); af0[7]=f2bf(fa1[3]);
    af1[0]=f2bf(fa2[0]); af1[1]=f2bf(fa2[1]); af1[2]=f2bf(fa2[2]); af1[3]=f2bf(fa2[3]);
    af1[4]=f2bf(fa3[0]); af1[5]=f2bf(fa3[1]); af1[6]=f2bf(fa3[2]); af1[7]=f2bf(fa3[3]);

    const size_t rowbase = (size_t)(r0 + rlane) * S + c0;

#pragma unroll
    for (int t = 0; t < 16; ++t) {
        const float* pb = Bb + (size_t)(c0 + t * 16 + rlane) * D + kg * 8;
        f32x4 g0 = *(const f32x4*)pb, g1 = *(const f32x4*)(pb + 4);
        f32x4 g2 = *(const f32x4*)(pb + 32), g3 = *(const f32x4*)(pb + 36);
        bf16x8 b0, b1;
        b0[0]=f2bf(g0[0]); b0[1]=f2bf(g0[1]); b0[2]=f2bf(g0[2]); b0[3]=f2bf(g0[3]);
        b0[4]=f2bf(g1[0]); b0[5]=f2bf(g1[1]); b0[6]=f2bf(g1[2]); b0[7]=f2bf(g1[3]);
        b1[0]=f2bf(g2[0]); b1[1]=f2bf(g2[1]); b1[2]=f2bf(g2[2]); b1[3]=f2bf(g2[3]);
        b1[4]=f2bf(g3[0]); b1[5]=f2bf(g3[1]); b1[6]=f2bf(g3[2]); b1[7]=f2bf(g3[3]);
        f32x4 z = {0.f, 0.f, 0.f, 0.f};
        z = __builtin_amdgcn_mfma_f32_16x16x32_bf16(b0, af0, z, 0, 0, 0);
        z = __builtin_amdgcn_mfma_f32_16x16x32_bf16(b1, af1, z, 0, 0, 0);
        f32x4 mkv = *(const f32x4*)(Mb + rowbase + t * 16 + kg * 4);
        z[0] *= mkv[0]; z[1] *= mkv[1]; z[2] *= mkv[2]; z[3] *= mkv[3];
        *(f32x4*)(Ob + rowbase + t * 16 + kg * 4) = z;
    }
}

extern "C" void kernel_launch(void* const* d_in, const int* in_sizes, int n_in,
                              void* d_out, int out_size, void* d_ws, size_t ws_size,
                              hipStream_t stream) {
    const float* a = (const float*)d_in[0];
    const float* b = (const float*)d_in[1];
    const float* m = (const float*)d_in[2];
    float* o = (float*)d_out;

    dim3 block(256);
    dim3 grid(S / 256, S / 64, 16);  // (col panels, row panels, b*h)

    const size_t ws_need = 2 * NELEM * sizeof(short) + NMASK;  // 8.4 + 8.4 MB
    if (ws_size >= ws_need) {
        short* a16 = (short*)d_ws;
        short* b16 = a16 + NELEM;
        unsigned char* m8 = (unsigned char*)(b16 + NELEM);
        // 1024 blocks cvt A + 1024 cvt B + 4096 pack mask
        hipLaunchKernelGGL(prep_kernel, dim3(6144), block, 0, stream, a, b, m, a16, b16, m8);
        hipLaunchKernelGGL(masked_mm_bf16_kernel, grid, block, 0, stream, a16, b16, m8, o);
    } else {
        hipLaunchKernelGGL(masked_mm_f32_kernel, grid, block, 0, stream, a, b, m, o);
    }
}

// Round 7
// 122.890 us; speedup vs baseline: 1.0846x; 1.0846x over previous
//
#include <hip/hip_runtime.h>

// MaskedDenseMatMul: out[b,h,q,k] = (sum_d a[b,h,q,d]*b[b,h,k,d]) * mask[b,0,q,k]
// B=2 H=8 S=2048 D=64, fp32 in/out.  Memory-bound on the 256 MiB output write.
//
// R7 design — software-pipelined reads (depth 2), per wave:
//  Diagnosis: all prior variants serialized {read-wait -> MFMA -> store} per
//  tile; under a write-saturated fabric the read round-trip (~2000 cy) stalls
//  each wave with only ~4 waves/SIMD to cover it (R1: VALUBusy 18%, occ 50%,
//  HBM 2.6 TB/s -> latency-bound).  Here each wave's 16 col-tiles run as 4
//  groups of 4 with group g+2's loads issued BEFORE group g's stores:
//  compiler auto-waitcnt becomes vmcnt(~16) -> ~1200 cy load prefetch distance
//  and 2 groups of store-drain slack per wave, times ~16 waves/CU of TLP.
//  No LDS, no barriers (nothing forces vmcnt(0)).  Mask loaded as f32x4
//  directly (R5 proved fetch *volume* is irrelevant; skip the pack pre-pass).

typedef __attribute__((ext_vector_type(8))) short bf16x8;
typedef __attribute__((ext_vector_type(4))) float f32x4;

static constexpr int S = 2048;
static constexpr int D = 64;
static constexpr size_t NELEM = (size_t)16 * S * D;   // elems per A/B input

__device__ inline short f2bf(float f) {
    union { float f; unsigned u; } v; v.f = f;
    unsigned r = (v.u + 0x7FFFu + ((v.u >> 16) & 1u)) >> 16;
    return (short)r;
}

// ---------------- pre-pass: A,B fp32 -> bf16 ---------------------------------
__global__ __launch_bounds__(256) void cvt_bf16_kernel(const float* __restrict__ a,
                                                       const float* __restrict__ b,
                                                       short* __restrict__ a16,
                                                       short* __restrict__ b16) {
    const int blk = blockIdx.x;
    const float* src = (blk < 1024) ? a : b;
    short* dst       = (blk < 1024) ? a16 : b16;
    size_t i = ((size_t)(blk & 1023) * 256 + threadIdx.x) * 8;
    f32x4 f0 = *(const f32x4*)(src + i);
    f32x4 f1 = *(const f32x4*)(src + i + 4);
    bf16x8 t;
    t[0] = f2bf(f0[0]); t[1] = f2bf(f0[1]); t[2] = f2bf(f0[2]); t[3] = f2bf(f0[3]);
    t[4] = f2bf(f1[0]); t[5] = f2bf(f1[1]); t[6] = f2bf(f1[2]); t[7] = f2bf(f1[3]);
    *(bf16x8*)(dst + i) = t;
}

// ---------------- main kernel: depth-2 pipelined groups ----------------------
__global__ __launch_bounds__(256) void masked_mm_bf16_kernel(
    const short* __restrict__ A16,
    const short* __restrict__ B16,
    const float* __restrict__ M,
    float* __restrict__ O) {

    const int bh   = blockIdx.z;             // 0..15
    const int bb   = bh >> 3;                // batch
    const int lane = threadIdx.x & 63;
    const int w    = threadIdx.x >> 6;       // wave 0..3

    const int r0 = blockIdx.y * 64 + w * 16; // wave's 16 output rows
    const int c0 = blockIdx.x * 256;         // block's 256 output cols

    const int rlane = lane & 15;             // MFMA operand row within 16
    const int kg    = lane >> 4;             // k-group 0..3

    const short* __restrict__ Ab = A16 + (size_t)bh * S * D;
    const short* __restrict__ Bb = B16 + (size_t)bh * S * D;
    const float* __restrict__ Mb = M + (size_t)bb * S * S;
    float* __restrict__ Ob       = O + (size_t)bh * S * S;

    // A fragments for the wave's 16 rows, K=64 (2 x K=32)
    bf16x8 af0 = *(const bf16x8*)(Ab + (size_t)(r0 + rlane) * D + 0  + kg * 8);
    bf16x8 af1 = *(const bf16x8*)(Ab + (size_t)(r0 + rlane) * D + 32 + kg * 8);

    const size_t rowbase = (size_t)(r0 + rlane) * S + c0;

    // double-buffered group state (indices compile-time after full unroll)
    bf16x8 pb0[2][4], pb1[2][4];
    f32x4  pm[2][4];

    auto issue = [&](int g) {
        if (g < 4) {
#pragma unroll
            for (int t = 0; t < 4; ++t) {
                const int cb = g * 4 + t;
                const short* pb = Bb + (size_t)(c0 + cb * 16 + rlane) * D + kg * 8;
                pb0[g & 1][t] = *(const bf16x8*)(pb);
                pb1[g & 1][t] = *(const bf16x8*)(pb + 32);
                pm[g & 1][t]  = *(const f32x4*)(Mb + rowbase + cb * 16 + kg * 4);
            }
        }
    };

    issue(0);
    issue(1);

#pragma unroll
    for (int g = 0; g < 4; ++g) {
        // consume group g (compiler inserts vmcnt leaving younger ops in flight)
        f32x4 acc[4];
#pragma unroll
        for (int t = 0; t < 4; ++t) {
            f32x4 z = {0.f, 0.f, 0.f, 0.f};
            // swapped operands: acc[j] = O[r0+rlane][c0+(g*4+t)*16+kg*4+j]
            z = __builtin_amdgcn_mfma_f32_16x16x32_bf16(pb0[g & 1][t], af0, z, 0, 0, 0);
            z = __builtin_amdgcn_mfma_f32_16x16x32_bf16(pb1[g & 1][t], af1, z, 0, 0, 0);
            f32x4 mkv = pm[g & 1][t];
            z[0] *= mkv[0]; z[1] *= mkv[1]; z[2] *= mkv[2]; z[3] *= mkv[3];
            acc[t] = z;
        }
        // prefetch group g+2 BEFORE storing group g: stores stay youngest in
        // the vmcnt FIFO -> next group's load-wait never drains them
        issue(g + 2);
#pragma unroll
        for (int t = 0; t < 4; ++t) {
            const int cb = g * 4 + t;
            *(f32x4*)(Ob + rowbase + cb * 16 + kg * 4) = acc[t];
        }
    }
}

// ---------------- fallback (ws too small): inline conversion -----------------
__global__ __launch_bounds__(256) void masked_mm_f32_kernel(
    const float* __restrict__ A,
    const float* __restrict__ B,
    const float* __restrict__ M,
    float* __restrict__ O) {

    const int bh   = blockIdx.z;
    const int bb   = bh >> 3;
    const int lane = threadIdx.x & 63;
    const int w    = threadIdx.x >> 6;
    const int r0 = blockIdx.y * 64 + w * 16;
    const int c0 = blockIdx.x * 256;
    const int rlane = lane & 15;
    const int kg    = lane >> 4;

    const float* __restrict__ Ab = A + (size_t)bh * S * D;
    const float* __restrict__ Bb = B + (size_t)bh * S * D;
    const float* __restrict__ Mb = M + (size_t)bb * S * S;
    float* __restrict__ Ob       = O + (size_t)bh * S * S;

    const float* pa = Ab + (size_t)(r0 + rlane) * D + kg * 8;
    f32x4 fa0 = *(const f32x4*)pa, fa1 = *(const f32x4*)(pa + 4);
    f32x4 fa2 = *(const f32x4*)(pa + 32), fa3 = *(const f32x4*)(pa + 36);
    bf16x8 af0, af1;
    af0[0]=f2bf(fa0[0]); af0[1]=f2bf(fa0[1]); af0[2]=f2bf(fa0[2]); af0[3]=f2bf(fa0[3]);
    af0[4]=f2bf(fa1[0]); af0[5]=f2bf(fa1[1]); af0[6]=f2bf(fa1[2]); af0[7]=f2bf(fa1[3]);
    af1[0]=f2bf(fa2[0]); af1[1]=f2bf(fa2[1]); af1[2]=f2bf(fa2[2]); af1[3]=f2bf(fa2[3]);
    af1[4]=f2bf(fa3[0]); af1[5]=f2bf(fa3[1]); af1[6]=f2bf(fa3[2]); af1[7]=f2bf(fa3[3]);

    const size_t rowbase = (size_t)(r0 + rlane) * S + c0;

#pragma unroll
    for (int t = 0; t < 16; ++t) {
        const float* pb = Bb + (size_t)(c0 + t * 16 + rlane) * D + kg * 8;
        f32x4 g0 = *(const f32x4*)pb, g1 = *(const f32x4*)(pb + 4);
        f32x4 g2 = *(const f32x4*)(pb + 32), g3 = *(const f32x4*)(pb + 36);
        bf16x8 b0, b1;
        b0[0]=f2bf(g0[0]); b0[1]=f2bf(g0[1]); b0[2]=f2bf(g0[2]); b0[3]=f2bf(g0[3]);
        b0[4]=f2bf(g1[0]); b0[5]=f2bf(g1[1]); b0[6]=f2bf(g1[2]); b0[7]=f2bf(g1[3]);
        b1[0]=f2bf(g2[0]); b1[1]=f2bf(g2[1]); b1[2]=f2bf(g2[2]); b1[3]=f2bf(g2[3]);
        b1[4]=f2bf(g3[0]); b1[5]=f2bf(g3[1]); b1[6]=f2bf(g3[2]); b1[7]=f2bf(g3[3]);
        f32x4 z = {0.f, 0.f, 0.f, 0.f};
        z = __builtin_amdgcn_mfma_f32_16x16x32_bf16(b0, af0, z, 0, 0, 0);
        z = __builtin_amdgcn_mfma_f32_16x16x32_bf16(b1, af1, z, 0, 0, 0);
        f32x4 mkv = *(const f32x4*)(Mb + rowbase + t * 16 + kg * 4);
        z[0] *= mkv[0]; z[1] *= mkv[1]; z[2] *= mkv[2]; z[3] *= mkv[3];
        *(f32x4*)(Ob + rowbase + t * 16 + kg * 4) = z;
    }
}

extern "C" void kernel_launch(void* const* d_in, const int* in_sizes, int n_in,
                              void* d_out, int out_size, void* d_ws, size_t ws_size,
                              hipStream_t stream) {
    const float* a = (const float*)d_in[0];
    const float* b = (const float*)d_in[1];
    const float* m = (const float*)d_in[2];
    float* o = (float*)d_out;

    dim3 block(256);
    dim3 grid(S / 256, S / 64, 16);  // (col panels, row panels, b*h)

    const size_t ws_need = 2 * NELEM * sizeof(short);  // 8.4 MB
    if (ws_size >= ws_need) {
        short* a16 = (short*)d_ws;
        short* b16 = a16 + NELEM;
        hipLaunchKernelGGL(cvt_bf16_kernel, dim3(2048), block, 0, stream, a, b, a16, b16);
        hipLaunchKernelGGL(masked_mm_bf16_kernel, grid, block, 0, stream, a16, b16, m, o);
    } else {
        hipLaunchKernelGGL(masked_mm_f32_kernel, grid, block, 0, stream, a, b, m, o);
    }
}

// Round 8
// 101.077 us; speedup vs baseline: 1.3186x; 1.2158x over previous
//
#include <hip/hip_runtime.h>

// MaskedDenseMatMul: out[b,h,q,k] = (sum_d a[b,h,q,d]*b[b,h,k,d]) * mask[b,0,q,k]
// B=2 H=8 S=2048 D=64, fp32 in/out.  Memory-bound on the 256 MiB output write.
//
// R8 design — store-last with a controlled register budget (R6 retried
// without the spill):
//  Wave lifetime vmem order: [A loads][16 B-frag loads][8 mask-u8 loads]
//  [16 MFMA][acc->LDS][LDS readback row-major (lgkm waits only)][mask select]
//  [8 stores, 512B-contiguous per half-wave, FINAL vmem ops -> never drained
//  by any later load-wait].  vmcnt is in-order on CDNA: any load issued after
//  a store forces that store's full round-trip on the next load-wait; every
//  prior variant had that pattern somewhere.  Fill kernel (6.6-7 TB/s at 10%
//  occupancy, zero loads) is the existence proof for un-drained store streams.
//  Wave = 16 rows x 128 cols (8 MFMA tiles) keeps B-staging at 64 VGPR ->
//  ~130 total, no spill.  Consecutive blocks write consecutive 2KB col-panels
//  of one 128KB row-stripe (dispatch-order-contiguous write stream).
//  Mask pre-packed to u8 (8.4 MB, L3-resident; 8 VGPR held per wave).

typedef __attribute__((ext_vector_type(8))) short bf16x8;
typedef __attribute__((ext_vector_type(4))) float f32x4;
typedef __attribute__((ext_vector_type(2))) unsigned int u32x2;

static constexpr int S = 2048;
static constexpr int D = 64;
static constexpr size_t NELEM = (size_t)16 * S * D;   // elems per A/B input
static constexpr size_t NMASK = (size_t)2 * S * S;    // mask elems (B*S*S)
static constexpr int RS = 132;                        // LDS row stride (pad)

__device__ inline short f2bf(float f) {
    union { float f; unsigned u; } v; v.f = f;
    unsigned r = (v.u + 0x7FFFu + ((v.u >> 16) & 1u)) >> 16;
    return (short)r;
}

// ------------- fused pre-pass: cvt A (1024 blk), cvt B (1024), pack mask (4096)
__global__ __launch_bounds__(256) void prep_kernel(const float* __restrict__ a,
                                                   const float* __restrict__ b,
                                                   const float* __restrict__ m,
                                                   short* __restrict__ a16,
                                                   short* __restrict__ b16,
                                                   unsigned char* __restrict__ m8) {
    const int blk = blockIdx.x;
    if (blk < 2048) {
        const float* src = (blk < 1024) ? a : b;
        short* dst       = (blk < 1024) ? a16 : b16;
        size_t i = ((size_t)(blk & 1023) * 256 + threadIdx.x) * 8;
        f32x4 f0 = *(const f32x4*)(src + i);
        f32x4 f1 = *(const f32x4*)(src + i + 4);
        bf16x8 t;
        t[0] = f2bf(f0[0]); t[1] = f2bf(f0[1]); t[2] = f2bf(f0[2]); t[3] = f2bf(f0[3]);
        t[4] = f2bf(f1[0]); t[5] = f2bf(f1[1]); t[6] = f2bf(f1[2]); t[7] = f2bf(f1[3]);
        *(bf16x8*)(dst + i) = t;
    } else {
        size_t i = ((size_t)(blk - 2048) * 256 + threadIdx.x) * 8;
        f32x4 f0 = *(const f32x4*)(m + i);
        f32x4 f1 = *(const f32x4*)(m + i + 4);
        unsigned w0 = 0, w1 = 0;
        w0 |= (f0[0] != 0.f ? 1u : 0u);
        w0 |= (f0[1] != 0.f ? 1u : 0u) << 8;
        w0 |= (f0[2] != 0.f ? 1u : 0u) << 16;
        w0 |= (f0[3] != 0.f ? 1u : 0u) << 24;
        w1 |= (f1[0] != 0.f ? 1u : 0u);
        w1 |= (f1[1] != 0.f ? 1u : 0u) << 8;
        w1 |= (f1[2] != 0.f ? 1u : 0u) << 16;
        w1 |= (f1[3] != 0.f ? 1u : 0u) << 24;
        u32x2 w; w[0] = w0; w[1] = w1;
        *(u32x2*)(m8 + i) = w;
    }
}

// ------------- main kernel ---------------------------------------------------
__global__ __launch_bounds__(256) void masked_mm_bf16_kernel(
    const short* __restrict__ A16,
    const short* __restrict__ B16,
    const unsigned char* __restrict__ M8,
    float* __restrict__ O) {

    __shared__ float lds[4][16][RS];          // 33792 B

    const int bh   = blockIdx.z;              // 0..15
    const int bb   = bh >> 3;                 // batch
    const int lane = threadIdx.x & 63;
    const int w    = threadIdx.x >> 6;        // wave 0..3

    const int r0  = blockIdx.y * 16;                 // stripe rows
    const int wc0 = blockIdx.x * 512 + w * 128;      // wave's 128 cols

    const int rlane = lane & 15;              // MFMA operand row within 16
    const int kg    = lane >> 4;              // k-group 0..3

    const short* __restrict__ Ab = A16 + (size_t)bh * S * D;
    const short* __restrict__ Bb = B16 + (size_t)bh * S * D;
    const unsigned char* __restrict__ Mb = M8 + (size_t)bb * S * S;
    float* __restrict__ Ob       = O + (size_t)bh * S * S;

    // ---- A fragments (16 rows, K=64) ----
    bf16x8 af0 = *(const bf16x8*)(Ab + (size_t)(r0 + rlane) * D + 0  + kg * 8);
    bf16x8 af1 = *(const bf16x8*)(Ab + (size_t)(r0 + rlane) * D + 32 + kg * 8);

    // ---- all B-fragment loads (8 tiles x 2) ----
    bf16x8 bs0[8], bs1[8];
#pragma unroll
    for (int t = 0; t < 8; ++t) {
        const short* pb = Bb + (size_t)(wc0 + t * 16 + rlane) * D + kg * 8;
        bs0[t] = *(const bf16x8*)(pb);
        bs1[t] = *(const bf16x8*)(pb + 32);
    }

    // ---- all mask loads (8 x uchar4, row-major store pattern) ----
    const int h2  = lane >> 5;   // row-half within pass
    const int c32 = lane & 31;   // col/4 within the wave's 128-col panel
    unsigned mrow[8];
#pragma unroll
    for (int p = 0; p < 8; ++p)
        mrow[p] = *(const unsigned*)(Mb + (size_t)(r0 + 2 * p + h2) * S + wc0 + c32 * 4);

    // ---- MFMA (swapped operands: acc[t][j] = O[r0+rlane][wc0+t*16+kg*4+j]) ----
    f32x4 acc[8];
#pragma unroll
    for (int t = 0; t < 8; ++t) {
        f32x4 z = {0.f, 0.f, 0.f, 0.f};
        z = __builtin_amdgcn_mfma_f32_16x16x32_bf16(bs0[t], af0, z, 0, 0, 0);
        z = __builtin_amdgcn_mfma_f32_16x16x32_bf16(bs1[t], af1, z, 0, 0, 0);
        acc[t] = z;
    }

    // ---- acc -> LDS (wave-private region; lgkm ordering only) ----
#pragma unroll
    for (int t = 0; t < 8; ++t)
        *(f32x4*)&lds[w][rlane][t * 16 + kg * 4] = acc[t];

    // ---- row-major readback + mask select + FINAL store burst ----
    // pass p: lanes 0..31 -> row 2p, lanes 32..63 -> row 2p+1; each half-wave
    // writes 512 B contiguous; stores are the wave's last vmem ops.
#pragma unroll
    for (int p = 0; p < 8; ++p) {
        const int rr = 2 * p + h2;
        f32x4 v = *(const f32x4*)&lds[w][rr][c32 * 4];
        const unsigned m = mrow[p];
        v[0] = (m & 0x000000FFu) ? v[0] : 0.f;
        v[1] = (m & 0x0000FF00u) ? v[1] : 0.f;
        v[2] = (m & 0x00FF0000u) ? v[2] : 0.f;
        v[3] = (m & 0xFF000000u) ? v[3] : 0.f;
        *(f32x4*)(Ob + (size_t)(r0 + rr) * S + wc0 + c32 * 4) = v;
    }
}

// ---------------- fallback (ws too small): inline conversion -----------------
__global__ __launch_bounds__(256) void masked_mm_f32_kernel(
    const float* __restrict__ A,
    const float* __restrict__ B,
    const float* __restrict__ M,
    float* __restrict__ O) {

    const int bh   = blockIdx.z;
    const int bb   = bh >> 3;
    const int lane = threadIdx.x & 63;
    const int w    = threadIdx.x >> 6;
    const int r0 = blockIdx.y * 64 + w * 16;
    const int c0 = blockIdx.x * 256;
    const int rlane = lane & 15;
    const int kg    = lane >> 4;

    const float* __restrict__ Ab = A + (size_t)bh * S * D;
    const float* __restrict__ Bb = B + (size_t)bh * S * D;
    const float* __restrict__ Mb = M + (size_t)bb * S * S;
    float* __restrict__ Ob       = O + (size_t)bh * S * S;

    const float* pa = Ab + (size_t)(r0 + rlane) * D + kg * 8;
    f32x4 fa0 = *(const f32x4*)pa, fa1 = *(const f32x4*)(pa + 4);
    f32x4 fa2 = *(const f32x4*)(pa + 32), fa3 = *(const f32x4*)(pa + 36);
    bf16x8 af0, af1;
    af0[0]=f2bf(fa0[0]); af0[1]=f2bf(fa0[1]); af0[2]=f2bf(fa0[2]); af0[3]=f2bf(fa0[3]);
    af0[4]=f2bf(fa1[0]); af0[5]=f2bf(fa1[1]); af0[6]=f2bf(fa1[2]); af0[7]=f2bf(fa1[3]);
    af1[0]=f2bf(fa2[0]); af1[1]=f2bf(fa2[1]); af1[2]=f2bf(fa2[2]); af1[3]=f2bf(fa2[3]);
    af1[4]=f2bf(fa3[0]); af1[5]=f2bf(fa3[1]); af1[6]=f2bf(fa3[2]); af1[7]=f2bf(fa3[3]);

    const size_t rowbase = (size_t)(r0 + rlane) * S + c0;

#pragma unroll
    for (int t = 0; t < 16; ++t) {
        const float* pb = Bb + (size_t)(c0 + t * 16 + rlane) * D + kg * 8;
        f32x4 g0 = *(const f32x4*)pb, g1 = *(const f32x4*)(pb + 4);
        f32x4 g2 = *(const f32x4*)(pb + 32), g3 = *(const f32x4*)(pb + 36);
        bf16x8 b0, b1;
        b0[0]=f2bf(g0[0]); b0[1]=f2bf(g0[1]); b0[2]=f2bf(g0[2]); b0[3]=f2bf(g0[3]);
        b0[4]=f2bf(g1[0]); b0[5]=f2bf(g1[1]); b0[6]=f2bf(g1[2]); b0[7]=f2bf(g1[3]);
        b1[0]=f2bf(g2[0]); b1[1]=f2bf(g2[1]); b1[2]=f2bf(g2[2]); b1[3]=f2bf(g2[3]);
        b1[4]=f2bf(g3[0]); b1[5]=f2bf(g3[1]); b1[6]=f2bf(g3[2]); b1[7]=f2bf(g3[3]);
        f32x4 z = {0.f, 0.f, 0.f, 0.f};
        z = __builtin_amdgcn_mfma_f32_16x16x32_bf16(b0, af0, z, 0, 0, 0);
        z = __builtin_amdgcn_mfma_f32_16x16x32_bf16(b1, af1, z, 0, 0, 0);
        f32x4 mkv = *(const f32x4*)(Mb + rowbase + t * 16 + kg * 4);
        z[0] *= mkv[0]; z[1] *= mkv[1]; z[2] *= mkv[2]; z[3] *= mkv[3];
        *(f32x4*)(Ob + rowbase + t * 16 + kg * 4) = z;
    }
}

extern "C" void kernel_launch(void* const* d_in, const int* in_sizes, int n_in,
                              void* d_out, int out_size, void* d_ws, size_t ws_size,
                              hipStream_t stream) {
    const float* a = (const float*)d_in[0];
    const float* b = (const float*)d_in[1];
    const float* m = (const float*)d_in[2];
    float* o = (float*)d_out;

    dim3 block(256);

    const size_t ws_need = 2 * NELEM * sizeof(short) + NMASK;  // 8.4 + 8.4 MB
    if (ws_size >= ws_need) {
        short* a16 = (short*)d_ws;
        short* b16 = a16 + NELEM;
        unsigned char* m8 = (unsigned char*)(b16 + NELEM);
        hipLaunchKernelGGL(prep_kernel, dim3(6144), block, 0, stream, a, b, m, a16, b16, m8);
        dim3 grid(4, 128, 16);  // (512-col panels, 16-row stripes, b*h)
        hipLaunchKernelGGL(masked_mm_bf16_kernel, grid, block, 0, stream, a16, b16, m8, o);
    } else {
        dim3 grid(S / 256, S / 64, 16);
        hipLaunchKernelGGL(masked_mm_f32_kernel, grid, block, 0, stream, a, b, m, o);
    }
}